// Round 10
// baseline (745.667 us; speedup 1.0000x reference)
//
#include <hip/hip_runtime.h>
#include <cstdint>
#include <cstddef>

// ---------------------------------------------------------------------------
// CapsNet forward. Round 10:
//  - conv2m: round-5 proven LDS kernel (unchanged; 153 us, 0 conflicts).
//  - squash + 3 routing iterations fused into ONE regular kernel k_route
//    (grid 256x256, <=47KB LDS -> all blocks co-resident) using a manual
//    monotonic-target grid barrier (device-scope atomicAdd + __threadfence).
//  - k_ut deleted: g2uv phase stages U-transpose in-LDS (padded rows).
//  - 4 kernel launches + 1 counter memset.
// Workspace (bytes):
//   h    [0, 52428800)           bf16 [b][pix400][ic256]
//   wt   [52428800, 63045632)    bf16 [k81][oc256][ic256]
//   pp   [63045632, 81920000)    f32  2 z-halves of [b][oc][36]
//   U    [81920000, 91357184)    f32  [b][ik]
//   dwT2 [91357184, 97255424)    f32  [co160][ik9216]
//   part [97255424, 102498304)   f32  [kc32][b256][co160]
//   bij  [102544384,102590464)   f32  [i][c]
//   outT [102590464,102754304)   f32  [co160][b256]
//   wb1  [112191488,112240640)   bf16 conv1 frag-linear weights
//   ctr  [112240640,112240704)   u32  grid-barrier counter (memset 0 each call)
// ---------------------------------------------------------------------------

typedef __attribute__((ext_vector_type(8))) short short8;
typedef __attribute__((ext_vector_type(4))) float f32x4;

#define PHALF 2359296

__device__ __forceinline__ unsigned short f2bf_rn(float x) {
    unsigned u = __float_as_uint(x);
    unsigned r = (u + 0x7fffu + ((u >> 16) & 1u)) >> 16;
    return (unsigned short)r;
}

// Merged prep. grid 417:
//   blk 0..255  : prim_w -> wt[k][oc][ic] bf16   (ocg=blk>>3, icg=blk&7)
//   blk 256     : conv1 weight frags wb1
//   blk 257..416: dw -> dwT2[co160][ik9216]
__global__ void k_prep(const float* __restrict__ w2, const float* __restrict__ cw,
                       const float* __restrict__ dw,
                       unsigned short* __restrict__ wt,
                       unsigned short* __restrict__ wb1,
                       float* __restrict__ dwT2) {
    __shared__ float lw[20736];
    int blk = blockIdx.x, t = threadIdx.x;
    if (blk < 256) {
        int ocg = blk >> 3, icg = blk & 7;
        for (int idx = t; idx < 20736; idx += 256) {
            int row = idx / 81, k = idx % 81;
            int oc_l = row >> 5, ic_l = row & 31;
            lw[idx] = w2[((size_t)(ocg * 8 + oc_l) * 256 + icg * 32 + ic_l) * 81 + k];
        }
        __syncthreads();
        for (int idx = t; idx < 2592; idx += 256) {
            int k = idx >> 5;
            int r = idx & 31;
            int oc_l = r >> 2, sl = r & 3;
            unsigned short hi8[8];
            #pragma unroll
            for (int j = 0; j < 8; j++)
                hi8[j] = f2bf_rn(lw[(oc_l * 32 + sl * 8 + j) * 81 + k]);
            size_t o = ((size_t)(k * 256 + ocg * 8 + oc_l)) * 256 + icg * 32 + sl * 8;
            *(uint4*)&wt[o] = *(uint4*)hi8;
        }
    } else if (blk == 256) {
        for (int idx = t; idx < 24576; idx += 256) {
            int j = idx & 7, lane = (idx >> 3) & 63;
            int q = (idx >> 9) % 3, nt = idx / 1536;
            int oc = nt * 16 + (lane & 15);
            int kg = q * 32 + (lane >> 4) * 8 + j;
            float v = (kg < 81) ? cw[oc * 81 + kg] : 0.f;
            wb1[idx] = f2bf_rn(v);
        }
    } else {
        int co = blk - 257;                   // 0..159
        int c = co >> 4, o = co & 15;
        const float* base = dw + c * 128 + o * 8;
        float* out = dwT2 + (size_t)co * 9216;
        for (int idx = t; idx < 9216; idx += 256) {
            int i = idx >> 3, k = idx & 7;
            out[idx] = base[(size_t)i * 1280 + k];
        }
    }
}

// MFMA conv1: grid (256 b, 2 ng), block 256 (4 waves). Validated rounds 6/8/9.
__global__ __launch_bounds__(256) void k_conv1m(
    const float* __restrict__ x, const unsigned short* __restrict__ wb1,
    const float* __restrict__ cb, unsigned short* __restrict__ h)
{
    __shared__ unsigned short xb[900];   // [30 rows][30 cols], zero-padded
    int b = blockIdx.x, ng = blockIdx.y, t = threadIdx.x;
    int w = t >> 6, l = t & 63;
    for (int idx = t; idx < 900; idx += 256) {
        int row = idx / 30, col = idx % 30;
        float v = (row < 28 && col < 28) ? x[(size_t)b * 784 + row * 28 + col] : 0.f;
        xb[idx] = f2bf_rn(v);
    }
    __syncthreads();
    int lane16 = l & 15, l4 = l >> 4;
    int ntile = (w == 0) ? 7 : 6;
    short8 afr[7][3];
    for (int i = 0; i < 7; i++) {
        if (i < ntile) {
            int mt = w + 4 * i;
            int pix = mt * 16 + lane16;
            int py = pix / 20, px = pix % 20;
            #pragma unroll
            for (int qq = 0; qq < 3; qq++) {
                int kbase = qq * 32 + l4 * 8;
                unsigned short tmp[8];
                int ky = kbase / 9, kx = kbase - 9 * (kbase / 9);
                #pragma unroll
                for (int j = 0; j < 8; j++) {
                    tmp[j] = xb[(py + ky) * 30 + px + kx];
                    kx++; if (kx == 9) { kx = 0; ky++; }
                }
                afr[i][qq] = *(short8*)tmp;
            }
        }
    }
    for (int nt0 = 0; nt0 < 8; nt0++) {
        int nt = ng * 8 + nt0;
        short8 bfr[3];
        #pragma unroll
        for (int qq = 0; qq < 3; qq++)
            bfr[qq] = *(const short8*)&wb1[(nt * 3 + qq) * 512 + l * 8];
        float bias = cb[nt * 16 + lane16];
        f32x4 acc[7] = {};
        for (int i = 0; i < 7; i++) {
            if (i < ntile) {
                #pragma unroll
                for (int qq = 0; qq < 3; qq++)
                    acc[i] = __builtin_amdgcn_mfma_f32_16x16x32_bf16(afr[i][qq], bfr[qq], acc[i], 0, 0, 0);
            }
        }
        for (int i = 0; i < 7; i++) {
            if (i < ntile) {
                int mt = w + 4 * i;
                int pixb = mt * 16 + l4 * 4;
                size_t base = ((size_t)b * 400 + pixb) * 256 + nt * 16 + lane16;
                #pragma unroll
                for (int r = 0; r < 4; r++) {
                    float v = fmaxf(acc[i][r] + bias, 0.f);
                    h[base + (size_t)r * 256] = f2bf_rn(v);
                }
            }
        }
    }
}

// Implicit-GEMM bf16 MFMA conv2 (round-5 proven config, unchanged).
__global__ __launch_bounds__(256) void k_conv2m(
    const unsigned short* __restrict__ h,
    const unsigned short* __restrict__ wt,
    float* __restrict__ pp)
{
    __shared__ unsigned short smem[24576];   // 49152 B
    const int t = threadIdx.x;
    const int w = t >> 6, l = t & 63;
    const int mb = blockIdx.x, nb = blockIdx.y, z = blockIdx.z;

    const unsigned short* src;
    int nld, sbase;
    unsigned rowbase[16];
    if (w < 2) {
        src = h; nld = 16; sbase = w * 8192;
        #pragma unroll
        for (int ld = 0; ld < 16; ld++) {
            int row = ld * 8 + (l >> 3);           // pixel local 0..127
            int c = l & 7;
            int g = c ^ (row & 7);
            int P = mb * 128 + row;
            int b = P / 36, o = P % 36;
            int oy = o / 6, ox = o % 6;
            rowbase[ld] = (unsigned)((b * 400 + oy * 40 + ox * 2) * 256 + z * 128 + w * 64 + g * 8);
        }
    } else {
        int hh = w - 2;
        src = wt; nld = 8; sbase = 16384 + hh * 4096;
        #pragma unroll
        for (int ld = 0; ld < 8; ld++) {
            int oc = ld * 8 + (l >> 3);            // 0..63
            int c = l & 7;
            int g = c ^ (oc & 7);
            rowbase[ld] = (unsigned)((nb * 64 + oc) * 256 + z * 128 + hh * 64 + g * 8);
        }
    }

    const int wm = w & 1, wn = w >> 1;
    const int lane16 = l & 15, q = l >> 4;

    f32x4 acc[4][2] = {};

    for (int ky = 0; ky < 9; ky++) {
        for (int kx = 0; kx < 9; kx++) {
            const unsigned kofs = (w < 2) ? (unsigned)((ky * 20 + kx) * 256)
                                          : (unsigned)((ky * 9 + kx) * 65536);
            __syncthreads();
            for (int ld = 0; ld < nld; ld++) {
                __builtin_amdgcn_global_load_lds(
                    (const __attribute__((address_space(1))) unsigned int*)(const void*)(src + rowbase[ld] + kofs),
                    (__attribute__((address_space(3))) unsigned int*)(void*)(smem + sbase + ld * 512),
                    16, 0, 0);
            }
            __syncthreads();
            #pragma unroll
            for (int hh = 0; hh < 2; hh++) {
                #pragma unroll
                for (int ic2 = 0; ic2 < 2; ic2++) {
                    short8 a[4], b[2];
                    #pragma unroll
                    for (int mt = 0; mt < 4; mt++) {
                        int pixL = wm * 64 + mt * 16 + lane16;
                        int ps = (ic2 * 4 + q) ^ (pixL & 7);
                        a[mt] = *(const short8*)(smem + hh * 8192 + pixL * 64 + ps * 8);
                    }
                    #pragma unroll
                    for (int nt = 0; nt < 2; nt++) {
                        int ocL = wn * 32 + nt * 16 + lane16;
                        int ps = (ic2 * 4 + q) ^ (ocL & 7);
                        b[nt] = *(const short8*)(smem + 16384 + hh * 4096 + ocL * 64 + ps * 8);
                    }
                    #pragma unroll
                    for (int mt = 0; mt < 4; mt++)
                        #pragma unroll
                        for (int nt = 0; nt < 2; nt++)
                            acc[mt][nt] = __builtin_amdgcn_mfma_f32_16x16x32_bf16(a[mt], b[nt], acc[mt][nt], 0, 0, 0);
                }
            }
        }
    }

    float* pout = pp + (size_t)z * PHALF;
    #pragma unroll
    for (int mt = 0; mt < 4; mt++) {
        int pixG = mb * 128 + wm * 64 + mt * 16 + q * 4;
        int b = pixG / 36, p36 = pixG % 36;
        #pragma unroll
        for (int nt = 0; nt < 2; nt++) {
            int oc = nb * 64 + wn * 32 + nt * 16 + lane16;
            f32x4 v = acc[mt][nt];
            *(f32x4*)&pout[((size_t)(b * 256 + oc)) * 36 + p36] = v;
        }
    }
}

// Monotonic-target grid barrier. All 256 blocks co-resident (grid==256,
// <=47KB LDS, >=1 block/CU). Release: __threadfence (device-scope L2 wb) +
// device-scope atomicAdd. Acquire: spin on agent-scope load + __threadfence.
__device__ __forceinline__ void gbar(unsigned* cnt, unsigned target) {
    __syncthreads();
    if (threadIdx.x == 0) {
        __threadfence();
        atomicAdd(cnt, 1u);
        while (__hip_atomic_load(cnt, __ATOMIC_RELAXED, __HIP_MEMORY_SCOPE_AGENT) < target)
            __builtin_amdgcn_s_sleep(4);
        __threadfence();
    }
    __syncthreads();
}

// Fused squash + 3 routing iterations. grid 256 x 256.
__global__ __launch_bounds__(256) void k_route(
    const float* __restrict__ pp, const float* __restrict__ prim_b,
    float* __restrict__ U, const float* __restrict__ dwT2,
    const float* __restrict__ dw,
    float* __restrict__ part, float* __restrict__ outT,
    float* __restrict__ bij, float* __restrict__ dout,
    unsigned* __restrict__ ctr)
{
    __shared__ __align__(16) float smem[11712];   // 46848 B, phase-overlaid
    const int bid = blockIdx.x, t = threadIdx.x;
    const int tc = t & 15, tb = t >> 4;
    unsigned tgt = 0;

    // ---------------- Phase S: squash over 1152 -> U ----------------
    for (int u = bid; u < 2048; u += 256) {
        __syncthreads();
        float* red = smem;
        int b = u >> 3, cap = u & 7;
        const float* pa = pp + ((size_t)b * 256 + cap * 32) * 36;
        const float* pc = pa + PHALF;
        float v[5];
        float ss = 0.f;
        #pragma unroll
        for (int j = 0; j < 5; j++) {
            int idx = t + j * 256;
            if (idx < 1152) {
                int ch_l = idx / 36;
                float val = pa[idx] + pc[idx] + prim_b[cap * 32 + ch_l];
                v[j] = val; ss += val * val;
            } else v[j] = 0.f;
        }
        for (int off = 32; off; off >>= 1) ss += __shfl_down(ss, off);
        if ((t & 63) == 0) red[t >> 6] = ss;
        __syncthreads();
        float n2 = red[0] + red[1] + red[2] + red[3];
        float f = (n2 / (1.0f + n2)) / (sqrtf(n2) + 1e-10f);
        #pragma unroll
        for (int j = 0; j < 5; j++) {
            int idx = t + j * 256;
            if (idx < 1152) U[(size_t)b * 9216 + idx * 8 + cap] = v[j] * f;
        }
    }
    tgt += 256; gbar(ctr, tgt);

    for (int iter = 0; iter < 3; iter++) {
        // ---------------- Phase A: gemm1 (inline softmax, c folded) ----------------
        {
            float* Us   = smem;          // 1152 (32x36)
            float* WsT  = smem + 1152;   // 5120
            float* cl   = smem + 6272;   // 360
            float* red  = smem + 6632;   // 256
            float* cmx  = smem + 6888;   // 10
            float* cinv = smem + 6898;   // 10
            int mb = bid & 7, kc = bid >> 3;

            if (iter > 0) {
                int c = t % 10, g = t / 10;          // 250 active, 25 groups
                float lmx = -1e30f;
                if (t < 250)
                    for (int i = g; i < 1152; i += 25) lmx = fmaxf(lmx, bij[i * 10 + c]);
                red[t] = lmx;
                __syncthreads();
                if (t < 10) {
                    float m = -1e30f;
                    #pragma unroll
                    for (int g2 = 0; g2 < 25; g2++) m = fmaxf(m, red[g2 * 10 + t]);
                    cmx[t] = m;
                }
                __syncthreads();
                float lsum = 0.f;
                if (t < 250) {
                    float m = cmx[c];
                    for (int i = g; i < 1152; i += 25) lsum += expf(bij[i * 10 + c] - m);
                }
                red[t] = lsum;
                __syncthreads();
                if (t < 10) {
                    float s2 = 0.f;
                    #pragma unroll
                    for (int g2 = 0; g2 < 25; g2++) s2 += red[g2 * 10 + t];
                    cinv[t] = 1.0f / s2;
                }
                __syncthreads();
                for (int idx = t; idx < 360; idx += 256) {
                    int i = kc * 36 + idx / 10, c2 = idx % 10;
                    cl[idx] = expf(bij[i * 10 + c2] - cmx[c2]) * cinv[c2];
                }
            }

            const float uscale = 1.0f / 1152.0f;
            float acc[2][10] = {};
            for (int ks = 0; ks < 9; ks++) {
                __syncthreads();
                {
                    int bb = t >> 3, k4 = t & 7;
                    *(float4*)&Us[bb * 36 + k4 * 4] =
                        *(const float4*)&U[(size_t)(mb * 32 + bb) * 9216 + kc * 288 + ks * 32 + k4 * 4];
                }
                #pragma unroll
                for (int pass = 0; pass < 5; pass++) {
                    int s = t + pass * 256;
                    int co = s >> 3, p = s & 7;
                    int kq = p ^ (co & 7);
                    int ikl = ks * 32 + kq * 4;
                    float4 v = *(const float4*)&dwT2[(size_t)co * 9216 + kc * 288 + ikl];
                    float sc = (iter == 0) ? uscale : cl[(ikl >> 3) * 10 + (co >> 4)];
                    v.x *= sc; v.y *= sc; v.z *= sc; v.w *= sc;
                    *(float4*)&WsT[s * 4] = v;
                }
                __syncthreads();
                float a0[32], a1[32];
                #pragma unroll
                for (int kq = 0; kq < 8; kq++) {
                    float4 v0 = *(const float4*)&Us[(tb * 2) * 36 + kq * 4];
                    float4 v1 = *(const float4*)&Us[(tb * 2 + 1) * 36 + kq * 4];
                    a0[kq * 4 + 0] = v0.x; a0[kq * 4 + 1] = v0.y; a0[kq * 4 + 2] = v0.z; a0[kq * 4 + 3] = v0.w;
                    a1[kq * 4 + 0] = v1.x; a1[kq * 4 + 1] = v1.y; a1[kq * 4 + 2] = v1.z; a1[kq * 4 + 3] = v1.w;
                }
                #pragma unroll
                for (int j = 0; j < 10; j++) {
                    int co = tc + 16 * j;
                    int cx = co & 7, cbase = co * 32;
                    #pragma unroll
                    for (int kq = 0; kq < 8; kq++) {
                        float4 wv = *(const float4*)&WsT[cbase + ((kq ^ cx) << 2)];
                        acc[0][j] += a0[kq * 4 + 0] * wv.x; acc[0][j] += a0[kq * 4 + 1] * wv.y;
                        acc[0][j] += a0[kq * 4 + 2] * wv.z; acc[0][j] += a0[kq * 4 + 3] * wv.w;
                        acc[1][j] += a1[kq * 4 + 0] * wv.x; acc[1][j] += a1[kq * 4 + 1] * wv.y;
                        acc[1][j] += a1[kq * 4 + 2] * wv.z; acc[1][j] += a1[kq * 4 + 3] * wv.w;
                    }
                }
            }
            #pragma unroll
            for (int r = 0; r < 2; r++)
                #pragma unroll
                for (int j = 0; j < 10; j++)
                    part[(size_t)kc * 40960 + (mb * 32 + tb * 2 + r) * 160 + tc + 16 * j] = acc[r][j];
        }
        tgt += 256; gbar(ctr, tgt);

        // ---------------- Phase B: redsq ----------------
        {
            float* sl  = smem;
            float* n2s = smem + 160;
            int b = bid;
            float s = 0.f;
            if (t < 160) {
                for (int kc = 0; kc < 32; kc++) s += part[(size_t)kc * 40960 + b * 160 + t];
                sl[t] = s;
            }
            __syncthreads();
            if (t < 16) {
                float n2 = 0.f;
                #pragma unroll
                for (int c = 0; c < 10; c++) { float v = sl[c * 16 + t]; n2 += v * v; }
                n2s[t] = n2;
            }
            __syncthreads();
            if (t < 160) {
                float n2 = n2s[t & 15];
                float f = (n2 / (1.0f + n2)) / (sqrtf(n2) + 1e-10f);
                float r = s * f;
                if (iter < 2) outT[(size_t)t * 256 + b] = r;
                else          dout[(size_t)b * 160 + t] = r;
            }
        }
        if (iter == 2) break;
        tgt += 256; gbar(ctr, tgt);

        // ---------------- Phase C: g2uv (stages U-transpose in LDS) ----------------
        for (int u = bid; u < 288; u += 256) {
            float* UsT = smem;           // 1152 (32 rows x 36 pad)
            float* OsT = smem + 1152;    // 5120
            float* dwl = smem + 6272;    // 5120
            float* sb  = smem + 11392;   // 320
            __syncthreads();
            for (int idx = t; idx < 5120; idx += 256)
                dwl[idx] = dw[(size_t)u * 5120 + idx];
            float acc[2][10] = {};
            for (int bs = 0; bs < 256; bs += 32) {
                __syncthreads();
                {   // stage U tile transposed: UsT[m][bb] = U[bs+bb][u*32+m]
                    int bb = t >> 3, m4 = t & 7;
                    float4 v = *(const float4*)&U[(size_t)(bs + bb) * 9216 + u * 32 + m4 * 4];
                    UsT[(m4 * 4 + 0) * 36 + bb] = v.x;
                    UsT[(m4 * 4 + 1) * 36 + bb] = v.y;
                    UsT[(m4 * 4 + 2) * 36 + bb] = v.z;
                    UsT[(m4 * 4 + 3) * 36 + bb] = v.w;
                }
                #pragma unroll
                for (int pass = 0; pass < 5; pass++) {
                    int s = t + pass * 256;
                    int co = s >> 3, p = s & 7;
                    int kq = p ^ (co & 7);
                    *(float4*)&OsT[s * 4] =
                        *(const float4*)&outT[(size_t)co * 256 + bs + kq * 4];
                }
                __syncthreads();
                float a0[32], a1[32];
                int m0 = tb * 2, m1 = tb * 2 + 1;
                #pragma unroll
                for (int kq = 0; kq < 8; kq++) {
                    float4 v0 = *(const float4*)&UsT[m0 * 36 + kq * 4];
                    float4 v1 = *(const float4*)&UsT[m1 * 36 + kq * 4];
                    a0[kq * 4 + 0] = v0.x; a0[kq * 4 + 1] = v0.y; a0[kq * 4 + 2] = v0.z; a0[kq * 4 + 3] = v0.w;
                    a1[kq * 4 + 0] = v1.x; a1[kq * 4 + 1] = v1.y; a1[kq * 4 + 2] = v1.z; a1[kq * 4 + 3] = v1.w;
                }
                #pragma unroll
                for (int j = 0; j < 10; j++) {
                    int co = tc + 16 * j;
                    int cx = co & 7, cbase = co * 32;
                    #pragma unroll
                    for (int kq = 0; kq < 8; kq++) {
                        float4 wv = *(const float4*)&OsT[cbase + ((kq ^ cx) << 2)];
                        acc[0][j] += a0[kq * 4 + 0] * wv.x; acc[0][j] += a0[kq * 4 + 1] * wv.y;
                        acc[0][j] += a0[kq * 4 + 2] * wv.z; acc[0][j] += a0[kq * 4 + 3] * wv.w;
                        acc[1][j] += a1[kq * 4 + 0] * wv.x; acc[1][j] += a1[kq * 4 + 1] * wv.y;
                        acc[1][j] += a1[kq * 4 + 2] * wv.z; acc[1][j] += a1[kq * 4 + 3] * wv.w;
                    }
                }
            }
            #pragma unroll
            for (int r = 0; r < 2; r++) {
                int ik_l = tb * 2 + r;
                int i_l = ik_l >> 3, k = ik_l & 7;
                #pragma unroll
                for (int j = 0; j < 10; j++) {
                    float v = acc[r][j] * dwl[i_l * 1280 + (j * 16 + tc) * 8 + k];
                    v += __shfl_down(v, 8, 16);
                    v += __shfl_down(v, 4, 16);
                    v += __shfl_down(v, 2, 16);
                    v += __shfl_down(v, 1, 16);
                    if (tc == 0) sb[ik_l * 10 + j] = v;
                }
            }
            __syncthreads();
            if (t < 40) {
                int i_l = t / 10, c = t % 10;
                float s = 0.f;
                #pragma unroll
                for (int kk = 0; kk < 8; kk++) s += sb[(i_l * 8 + kk) * 10 + c];
                size_t o = (size_t)(u * 4 + i_l) * 10 + c;
                float val = s * (1.0f / 256.0f);
                if (iter == 0) bij[o] = val;
                else           bij[o] += val;
            }
        }
        tgt += 256; gbar(ctr, tgt);
    }
}

extern "C" void kernel_launch(void* const* d_in, const int* in_sizes, int n_in,
                              void* d_out, int out_size, void* d_ws, size_t ws_size,
                              hipStream_t stream) {
    const float* x      = (const float*)d_in[0];
    const float* conv_w = (const float*)d_in[1];
    const float* conv_b = (const float*)d_in[2];
    const float* prim_w = (const float*)d_in[3];
    const float* prim_b = (const float*)d_in[4];
    const float* dw     = (const float*)d_in[5];

    char* wsb = (char*)d_ws;
    unsigned short* h   = (unsigned short*)(wsb);
    unsigned short* wt  = (unsigned short*)(wsb + 52428800);
    float* pp   = (float*)(wsb + 63045632);
    float* U    = (float*)(wsb + 81920000);
    float* dwT2 = (float*)(wsb + 91357184);
    float* part = (float*)(wsb + 97255424);
    float* bij  = (float*)(wsb + 102544384);
    float* outT = (float*)(wsb + 102590464);
    unsigned short* wb1 = (unsigned short*)(wsb + 112191488);
    unsigned* ctr = (unsigned*)(wsb + 112240640);
    float* dout = (float*)d_out;

    hipMemsetAsync(ctr, 0, 64, stream);
    k_prep<<<417, 256, 0, stream>>>(prim_w, conv_w, dw, wt, wb1, dwT2);
    k_conv1m<<<dim3(256, 2), 256, 0, stream>>>(x, wb1, conv_b, h);
    k_conv2m<<<dim3(72, 4, 2), 256, 0, stream>>>(h, wt, pp);
    k_route<<<256, 256, 0, stream>>>(pp, prim_b, U, dwT2, dw,
                                     part, outT, bij, dout, ctr);
}